// Round 2
// baseline (234.136 us; speedup 1.0000x reference)
//
#include <hip/hip_runtime.h>
#include <math.h>

#define NN 50000      // nodes
#define NE 600000     // edges
#define NR 64         // relations
#define DD 128        // dim

typedef __attribute__((ext_vector_type(2))) _Float16 h2;
typedef __attribute__((ext_vector_type(4))) _Float16 h4;
typedef __attribute__((ext_vector_type(8))) _Float16 h8;   // MFMA A/B frag (4 VGPRs)
typedef __attribute__((ext_vector_type(4))) float f32x4;   // MFMA C/D frag

// ---------- fast math helpers ----------

// Odd Taylor tanh (to x^5) on packed f16: trunc error <= 4.2e-4 at |x|=0.5
// (typ. ~1e-6 at 3 sigma of the x = ent+rel distribution) — below the f16
// input-quantization noise already in the pipeline.
__device__ __forceinline__ h2 tanh_h2(h2 x) {
    const h2 C5 = {(_Float16)0.1333333333f,  (_Float16)0.1333333333f};
    const h2 C3 = {(_Float16)-0.3333333333f, (_Float16)-0.3333333333f};
    const h2 ONE = {(_Float16)1.f, (_Float16)1.f};
    h2 x2 = x * x;
    h2 p = x2 * C5 + C3;      // v_pk_fma_f16
    p = x2 * p + ONE;
    return x * p;
}

template <int CTRL, int ROW_MASK>
__device__ __forceinline__ float dpp_add(float x) {
    int xi = __builtin_bit_cast(int, x);
    int yi = __builtin_amdgcn_update_dpp(0, xi, CTRL, ROW_MASK, 0xF, true);
    return x + __builtin_bit_cast(float, yi);
}

// ---------- fused prep: f16 staging (ent/rel/W) + CSR-bucket build ----------
// blocks [0,8): rel->relh | [8,40): wpack | [40,6290): ent->Ah cols 0..127
// Edge fill is MERGED into the first ~293 ent blocks: those threads issue
// 8 edge atomics (rank assignment) alongside their ent float4 copy, so the
// device-scope RMW latency hides under the staging bandwidth stream instead
// of idling dedicated fill waves. Bucket stores are nontemporal (scattered
// 4B, no reuse before eviction — skip write-allocate).

__global__ __launch_bounds__(256) void prep_k(const float* __restrict__ ent,
                                              const float* __restrict__ rel,
                                              const float* __restrict__ W,
                                              const int* __restrict__ edst,
                                              const int* __restrict__ enbr,
                                              const int* __restrict__ erel,
                                              _Float16* __restrict__ Ah,
                                              _Float16* __restrict__ relh,
                                              _Float16* __restrict__ wp,
                                              int* __restrict__ deg,
                                              int* __restrict__ bucket) {
    int b = blockIdx.x;
    if (b < 8) {
        int tid = b * 256 + threadIdx.x;            // NR*32 = 2048
        float4 v = *(const float4*)&rel[tid * 4];
        h4 o = {(_Float16)v.x, (_Float16)v.y, (_Float16)v.z, (_Float16)v.w};
        *(h4*)&relh[tid * 4] = o;
    } else if (b < 40) {
        int tid = (b - 8) * 256 + threadIdx.x;      // 8192
        int lane = tid & 63;
        int ct   = (tid >> 6) & 7;
        int ks   = (tid >> 9) & 7;
        int l    = tid >> 12;
        int q = lane >> 4, n = lane & 15;
        const float* Wl = W + (size_t)l * 256 * 128;
        _Float16* dst = wp + ((((size_t)l * 8 + ks) * 8 + ct) * 64 + lane) * 8;
#pragma unroll
        for (int j = 0; j < 8; ++j) {
            int k = ks * 32 + q * 8 + j;
            dst[j] = (_Float16)Wl[(size_t)k * 128 + ct * 16 + n];
        }
    } else {
        int tid = (b - 40) * 256 + threadIdx.x;     // NN*32 exactly
        bool ew = tid < (NE / 8);                   // 75000 edge-bearing threads
        int e = tid * 8;

        // issue edge loads first (6 int4), fully independent of the copy
        int4 d0, d1, n0, n1, r0, r1;
        if (ew) {
            d0 = *(const int4*)&edst[e];
            d1 = *(const int4*)&edst[e + 4];
            n0 = *(const int4*)&enbr[e];
            n1 = *(const int4*)&enbr[e + 4];
            r0 = *(const int4*)&erel[e];
            r1 = *(const int4*)&erel[e + 4];
        }

        int node = tid >> 5, c = tid & 31;
        float4 v = *(const float4*)&ent[(size_t)node * DD + c * 4];

        int k0, k1, k2, k3, k4, k5, k6, k7;
        if (ew) {   // 8 independent device-scope RMWs in flight per thread
            k0 = atomicAdd(&deg[d0.x], 1);
            k1 = atomicAdd(&deg[d0.y], 1);
            k2 = atomicAdd(&deg[d0.z], 1);
            k3 = atomicAdd(&deg[d0.w], 1);
            k4 = atomicAdd(&deg[d1.x], 1);
            k5 = atomicAdd(&deg[d1.y], 1);
            k6 = atomicAdd(&deg[d1.z], 1);
            k7 = atomicAdd(&deg[d1.w], 1);
        }

        h4 o = {(_Float16)v.x, (_Float16)v.y, (_Float16)v.z, (_Float16)v.w};
        *(h4*)&Ah[(size_t)node * 256 + c * 4] = o;

        if (ew) {
            // P(deg>64) ~ 1e-19 for Poisson(12); guard is corruption-proofing
            if (k0 < 64) __builtin_nontemporal_store(n0.x | (r0.x << 16), &bucket[d0.x * 64 + k0]);
            if (k1 < 64) __builtin_nontemporal_store(n0.y | (r0.y << 16), &bucket[d0.y * 64 + k1]);
            if (k2 < 64) __builtin_nontemporal_store(n0.z | (r0.z << 16), &bucket[d0.z * 64 + k2]);
            if (k3 < 64) __builtin_nontemporal_store(n0.w | (r0.w << 16), &bucket[d0.w * 64 + k3]);
            if (k4 < 64) __builtin_nontemporal_store(n1.x | (r1.x << 16), &bucket[d1.x * 64 + k4]);
            if (k5 < 64) __builtin_nontemporal_store(n1.y | (r1.y << 16), &bucket[d1.y * 64 + k5]);
            if (k6 < 64) __builtin_nontemporal_store(n1.z | (r1.z << 16), &bucket[d1.z * 64 + k6]);
            if (k7 < 64) __builtin_nontemporal_store(n1.w | (r1.w << 16), &bucket[d1.w * 64 + k7]);
        }
    }
}

// ---------- per-node attention aggregate v5 (padded-bucket CSR) ----------
// 1 node/wave; 4 edges/iter as 4 groups of 16 lanes; lane owns 8 dims (one
// 16B h8 load each for nb and rl). Shared reduce: 4 DPP row_shr adds reduce
// all 4 groups at once, ds_swizzle 0x1F0 broadcasts each row's lane15 back.
// One exp per 4 edges. Data+pk pipelined 1 iter ahead; unroll 2 makes the
// rotation static (no v_mov churn) and deepens effective prefetch to 2.
// No-max softmax (|s|<=3.5 -> exp<=33; l kept in f32).

__global__ __launch_bounds__(256) void agg_k(const _Float16* __restrict__ Ah,
                                             const _Float16* __restrict__ Aq,
                                             const _Float16* __restrict__ relh,
                                             const int* __restrict__ deg_,
                                             const int* __restrict__ bucket,
                                             _Float16* __restrict__ Ah_out) {
    int lane = threadIdx.x & 63;
    int grp  = lane >> 4;                   // edge slot within iteration
    int t16  = lane & 15;                   // dim-chunk within group
    int wid  = threadIdx.x >> 6;
    int node = blockIdx.x * 4 + wid;        // NN%4==0, no tail
    int dg = deg_[node];

    unsigned dof = (unsigned)t16 * 8u;      // first of this lane's 8 dims
    h8 qv = *(const h8*)&Aq[(unsigned)node * 256u + dof];
    h2 q0 = {qv[0], qv[1]}, q1 = {qv[2], qv[3]}, q2 = {qv[4], qv[5]}, q3 = {qv[6], qv[7]};

    float l = 0.f;
    h2 acc0 = {(_Float16)0.f, (_Float16)0.f};
    h2 acc1 = acc0, acc2 = acc0, acc3 = acc0;

    if (dg > 0) {
        int e0 = node * 64;                 // padded bucket row
        int e1 = e0 + dg;
        int iters = (dg + 3) >> 2;
        int last = e1 - 1;
        int ei = e0 + grp;                  // this group's edge for iter 0

        // prologue: pk + data for iter 0, pk for iter 1
        int pk_c = bucket[min(ei, last)];
        h8 nb_c = *(const h8*)&Ah[(unsigned)(pk_c & 0xFFFF) * 256u + dof];
        h8 rl_c = *(const h8*)&relh[(unsigned)(pk_c >> 16) * 128u + dof];
        int pk_n = bucket[min(ei + 4, last)];

#pragma unroll 2
        for (int it = 0; it < iters; ++it) {
            // prefetch iter it+2's pk and iter it+1's data
            int pk_n2 = bucket[min(ei + 8, last)];
            h8 nb_n = *(const h8*)&Ah[(unsigned)(pk_n & 0xFFFF) * 256u + dof];
            h8 rl_n = *(const h8*)&relh[(unsigned)(pk_n >> 16) * 128u + dof];

            h2 n0 = {nb_c[0], nb_c[1]}, n1 = {nb_c[2], nb_c[3]};
            h2 n2 = {nb_c[4], nb_c[5]}, n3 = {nb_c[6], nb_c[7]};
            h2 r0 = {rl_c[0], rl_c[1]}, r1 = {rl_c[2], rl_c[3]};
            h2 r2 = {rl_c[4], rl_c[5]}, r3 = {rl_c[6], rl_c[7]};

            h2 sd = n0 * tanh_h2(q0 + r0);
            sd = n1 * tanh_h2(q1 + r1) + sd;
            sd = n2 * tanh_h2(q2 + r2) + sd;
            sd = n3 * tanh_h2(q3 + r3) + sd;
            float s = (float)sd.x + (float)sd.y;

            // reduce all 4 groups at once: 4 row_shr adds -> lane15 of each row
            s = dpp_add<0x111, 0xF>(s);
            s = dpp_add<0x112, 0xF>(s);
            s = dpp_add<0x114, 0xF>(s);
            s = dpp_add<0x118, 0xF>(s);
            // broadcast each row's lane15 to the whole row: src=(lane&0x10)|0xF
            int si = __builtin_amdgcn_ds_swizzle(__builtin_bit_cast(int, s), 0x1F0);
            s = __builtin_bit_cast(float, si);

            float p = (ei < e1) ? __expf(s) : 0.f;
            l += p;
            _Float16 ph = (_Float16)p;
            h2 p2 = {ph, ph};
            acc0 = p2 * n0 + acc0;
            acc1 = p2 * n1 + acc1;
            acc2 = p2 * n2 + acc2;
            acc3 = p2 * n3 + acc3;

            ei += 4;
            pk_c = pk_n; pk_n = pk_n2;
            nb_c = nb_n; rl_c = rl_n;
        }

        // combine the 4 groups (same dims, disjoint edge subsets): xor 16, 32
#pragma unroll
        for (int off = 16; off <= 32; off <<= 1) {
            acc0 += __builtin_bit_cast(h2, __shfl_xor(__builtin_bit_cast(int, acc0), off, 64));
            acc1 += __builtin_bit_cast(h2, __shfl_xor(__builtin_bit_cast(int, acc1), off, 64));
            acc2 += __builtin_bit_cast(h2, __shfl_xor(__builtin_bit_cast(int, acc2), off, 64));
            acc3 += __builtin_bit_cast(h2, __shfl_xor(__builtin_bit_cast(int, acc3), off, 64));
            l += __shfl_xor(l, off, 64);
        }
    }

    float inv = (dg > 0) ? __builtin_amdgcn_rcpf(l) : 0.f;
    if (grp == 0) {
        _Float16 ih = (_Float16)inv;
        h2 iv = {ih, ih};
        h2 o0 = acc0 * iv, o1 = acc1 * iv, o2 = acc2 * iv, o3 = acc3 * iv;
        h8 o = {o0.x, o0.y, o1.x, o1.y, o2.x, o2.y, o3.x, o3.y};
        *(h8*)&Ah_out[(unsigned)node * 256u + 128u + dof] = o;
    }
}

// ---------- MFMA update: C[50000,128] = Ah[50000,256] @ W + b, fused epilogue ----
// LAST=false: write next layer's Ah only. LAST=true: write f32 out only.

template <bool LAST>
__global__ __launch_bounds__(256) void upd_k(const _Float16* __restrict__ Ah,
                                             const _Float16* __restrict__ wp,
                                             const float* __restrict__ bl,
                                             const int* __restrict__ deg_,
                                             const float* __restrict__ ent,
                                             float* __restrict__ out,
                                             _Float16* __restrict__ Ahn) {
    int lane = threadIdx.x & 63, wid = threadIdx.x >> 6;
    int quad = lane >> 4, n16 = lane & 15;
    int row0 = (blockIdx.x * 4 + wid) * 16;
    int arow = min(row0 + n16, NN - 1);          // clamped A row (pad rows discarded)

    f32x4 acc[8];
#pragma unroll
    for (int ct = 0; ct < 8; ++ct) acc[ct] = (f32x4){0.f, 0.f, 0.f, 0.f};

    const h8* aptr = (const h8*)(Ah + (size_t)arow * 256 + quad * 8);
#pragma unroll
    for (int ks = 0; ks < 8; ++ks) {
        h8 af = aptr[ks * 4];                    // stride 32 f16 per k-step
        const h8* bp = (const h8*)(wp + (((size_t)ks * 8) * 64 + lane) * 8);
#pragma unroll
        for (int ct = 0; ct < 8; ++ct) {
            h8 bfrag = bp[ct * 64];              // per-ct stride 64*8 f16
            acc[ct] = __builtin_amdgcn_mfma_f32_16x16x32_f16(af, bfrag, acc[ct], 0, 0, 0);
        }
    }

    float bias[8];
#pragma unroll
    for (int ct = 0; ct < 8; ++ct) bias[ct] = bl[ct * 16 + n16];

#pragma unroll
    for (int r = 0; r < 4; ++r) {
        int orow = row0 + quad * 4 + r;
        float h[8];
        float ss = 0.f;
#pragma unroll
        for (int ct = 0; ct < 8; ++ct) {
            float v = acc[ct][r] + bias[ct];
            v = (v > 0.f) ? v : 0.01f * v;
            h[ct] = v;
            ss += v * v;
        }
        ss = dpp_add<0x111, 0xF>(ss);
        ss = dpp_add<0x112, 0xF>(ss);
        ss = dpp_add<0x114, 0xF>(ss);
        ss = dpp_add<0x118, 0xF>(ss);
        ss = __shfl(ss, 15, 16);                 // broadcast lane15 of each 16-group
        float rinv = rsqrtf(ss);

        if (orow < NN) {
            bool iso = deg_[orow] == 0;
#pragma unroll
            for (int ct = 0; ct < 8; ++ct) {
                int col = ct * 16 + n16;
                float v = h[ct] * rinv;
                if (iso) v = ent[(size_t)orow * DD + col];
                if (LAST) out[(size_t)orow * DD + col] = v;
                else      Ahn[(size_t)orow * 256 + col] = (_Float16)v;
            }
        }
    }
}

// ---------- launch ----------

extern "C" void kernel_launch(void* const* d_in, const int* in_sizes, int n_in,
                              void* d_out, int out_size, void* d_ws, size_t ws_size,
                              hipStream_t stream) {
    const float* ent = (const float*)d_in[0];   // [NN, DD]
    const float* rel = (const float*)d_in[1];   // [NR, DD]
    const float* W   = (const float*)d_in[2];   // [2, 2*DD, DD]
    const float* b   = (const float*)d_in[3];   // [2, DD]
    const int* edst  = (const int*)d_in[4];
    const int* enbr  = (const int*)d_in[5];
    const int* erel  = (const int*)d_in[6];
    float* out = (float*)d_out;                 // [NN, DD]

    char* ws = (char*)d_ws;
    size_t off = 0;
    auto alloc = [&](size_t bytes) -> void* {
        void* p = ws + off;
        off += (bytes + 255) & ~(size_t)255;
        return p;
    };
    int* deg       = (int*)alloc((size_t)NN * 4);
    int* bucket    = (int*)alloc((size_t)NN * 64 * 4);   // 12.8 MB padded CSR
    _Float16* Ah0  = (_Float16*)alloc((size_t)NN * 256 * 2);
    _Float16* Ah1  = (_Float16*)alloc((size_t)NN * 256 * 2);
    _Float16* wp   = (_Float16*)alloc((size_t)2 * 8 * 8 * 64 * 8 * 2);
    _Float16* relh = (_Float16*)alloc((size_t)NR * DD * 2);

    // staging + bucket-CSR build in ONE kernel (edge work merged into the
    // early ent blocks so atomic latency hides under the copy stream)
    hipMemsetAsync(deg, 0, (size_t)NN * 4, stream);
    prep_k<<<6290, 256, 0, stream>>>(ent, rel, W, edst, enbr, erel,
                                     Ah0, relh, wp, deg, bucket);

    const _Float16* wp0 = wp;
    const _Float16* wp1 = wp + (size_t)8 * 8 * 64 * 8;
    int ublocks = (NN + 63) / 64;   // 782

    // layer 0: nb from Ah0, q from Ah0 (cols 0..127 = ent f16, kept pristine)
    agg_k<<<NN / 4, 256, 0, stream>>>(Ah0, Ah0, relh, deg, bucket, Ah0);
    upd_k<false><<<ublocks, 256, 0, stream>>>(Ah0, wp0, b, deg, ent, out, Ah1);

    // layer 1: nb from Ah1, q from Ah0
    agg_k<<<NN / 4, 256, 0, stream>>>(Ah1, Ah0, relh, deg, bucket, Ah1);
    upd_k<true><<<ublocks, 256, 0, stream>>>(Ah1, wp1, b + DD, deg, ent, out, Ah0);
}

// Round 3
// 221.888 us; speedup vs baseline: 1.0552x; 1.0552x over previous
//
#include <hip/hip_runtime.h>
#include <math.h>

#define NN 50000      // nodes
#define NE 600000     // edges
#define NR 64         // relations
#define DD 128        // dim
#define FB 586        // fill blocks: NE/4 edges-per-thread batches of 256
#define DEGS 16       // deg stride: one counter per 64B line (atomic contention probe)

typedef __attribute__((ext_vector_type(2))) _Float16 h2;
typedef __attribute__((ext_vector_type(4))) _Float16 h4;
typedef __attribute__((ext_vector_type(8))) _Float16 h8;   // MFMA A/B frag (4 VGPRs)
typedef __attribute__((ext_vector_type(4))) float f32x4;   // MFMA C/D frag

// ---------- fast math helpers ----------

// Odd Taylor tanh (to x^5) on packed f16: trunc error <= 4.2e-4 at |x|=0.5
// (typ. ~1e-6 at 3 sigma of the x = ent+rel distribution) — below the f16
// input-quantization noise already in the pipeline.
__device__ __forceinline__ h2 tanh_h2(h2 x) {
    const h2 C5 = {(_Float16)0.1333333333f,  (_Float16)0.1333333333f};
    const h2 C3 = {(_Float16)-0.3333333333f, (_Float16)-0.3333333333f};
    const h2 ONE = {(_Float16)1.f, (_Float16)1.f};
    h2 x2 = x * x;
    h2 p = x2 * C5 + C3;      // v_pk_fma_f16
    p = x2 * p + ONE;
    return x * p;
}

template <int CTRL, int ROW_MASK>
__device__ __forceinline__ float dpp_add(float x) {
    int xi = __builtin_bit_cast(int, x);
    int yi = __builtin_amdgcn_update_dpp(0, xi, CTRL, ROW_MASK, 0xF, true);
    return x + __builtin_bit_cast(float, yi);
}

// ---------- fused prep: f16 staging (ent/rel/W) + CSR-bucket build ----------
// blocks [0,FB): edge fill (deg atomic rank -> 64-slot padded bucket)
//        [FB,FB+6250): ent->Ah cols 0..127 | [FB+6250,FB+6258): rel->relh
//        [FB+6258,FB+6290): wpack
// Fill blocks FIRST (dedicated waves — R2 showed merging them into copy
// threads serializes the wave on atomic returns and is NET WORSE). deg is
// line-padded (DEGS): one counter per 64B line to kill cross-XCD line
// contention on the 600k atomic RMWs.

__global__ __launch_bounds__(256) void prep_k(const float* __restrict__ ent,
                                              const float* __restrict__ rel,
                                              const float* __restrict__ W,
                                              const int* __restrict__ edst,
                                              const int* __restrict__ enbr,
                                              const int* __restrict__ erel,
                                              _Float16* __restrict__ Ah,
                                              _Float16* __restrict__ relh,
                                              _Float16* __restrict__ wp,
                                              int* __restrict__ deg,
                                              int* __restrict__ bucket) {
    int b = blockIdx.x;
    if (b < FB) {
        int e = (b * 256 + threadIdx.x) * 4;
        if (e < NE) {                       // NE%4==0: int4 fully in or out
            int4 d  = *(const int4*)&edst[e];
            int4 nb = *(const int4*)&enbr[e];
            int4 rl = *(const int4*)&erel[e];
            int r0 = atomicAdd(&deg[d.x * DEGS], 1);
            int r1 = atomicAdd(&deg[d.y * DEGS], 1);
            int r2 = atomicAdd(&deg[d.z * DEGS], 1);
            int r3 = atomicAdd(&deg[d.w * DEGS], 1);
            // P(deg>64) ~ 1e-19 for Poisson(12); guard is corruption-proofing
            if (r0 < 64) bucket[d.x * 64 + r0] = nb.x | (rl.x << 16);
            if (r1 < 64) bucket[d.y * 64 + r1] = nb.y | (rl.y << 16);
            if (r2 < 64) bucket[d.z * 64 + r2] = nb.z | (rl.z << 16);
            if (r3 < 64) bucket[d.w * 64 + r3] = nb.w | (rl.w << 16);
        }
    } else if (b < FB + 6250) {
        int tid = (b - FB) * 256 + threadIdx.x;     // NN*32 exactly
        int node = tid >> 5, c = tid & 31;
        float4 v = *(const float4*)&ent[(size_t)node * DD + c * 4];
        h4 o = {(_Float16)v.x, (_Float16)v.y, (_Float16)v.z, (_Float16)v.w};
        *(h4*)&Ah[(size_t)node * 256 + c * 4] = o;
    } else if (b < FB + 6258) {
        int tid = (b - FB - 6250) * 256 + threadIdx.x;   // NR*32 = 2048
        float4 v = *(const float4*)&rel[tid * 4];
        h4 o = {(_Float16)v.x, (_Float16)v.y, (_Float16)v.z, (_Float16)v.w};
        *(h4*)&relh[tid * 4] = o;
    } else {
        int tid = (b - FB - 6258) * 256 + threadIdx.x;   // 8192
        int lane = tid & 63;
        int ct   = (tid >> 6) & 7;
        int ks   = (tid >> 9) & 7;
        int l    = tid >> 12;
        int q = lane >> 4, n = lane & 15;
        const float* Wl = W + (size_t)l * 256 * 128;
        _Float16* dst = wp + ((((size_t)l * 8 + ks) * 8 + ct) * 64 + lane) * 8;
#pragma unroll
        for (int j = 0; j < 8; ++j) {
            int k = ks * 32 + q * 8 + j;
            dst[j] = (_Float16)Wl[(size_t)k * 128 + ct * 16 + n];
        }
    }
}

// ---------- per-node attention aggregate v5 (padded-bucket CSR) ----------
// 1 node/wave; 4 edges/iter as 4 groups of 16 lanes; lane owns 8 dims (one
// 16B h8 load each for nb and rl). Shared reduce: 4 DPP row_shr adds reduce
// all 4 groups at once, ds_swizzle 0x1F0 broadcasts each row's lane15 back.
// One exp per 4 edges. Data+pk pipelined 1 iter ahead; unroll 2 makes the
// rotation static (no v_mov churn) and deepens effective prefetch to 2.
// No-max softmax (|s|<=3.5 -> exp<=33; l kept in f32).

__global__ __launch_bounds__(256) void agg_k(const _Float16* __restrict__ Ah,
                                             const _Float16* __restrict__ Aq,
                                             const _Float16* __restrict__ relh,
                                             const int* __restrict__ deg_,
                                             const int* __restrict__ bucket,
                                             _Float16* __restrict__ Ah_out) {
    int lane = threadIdx.x & 63;
    int grp  = lane >> 4;                   // edge slot within iteration
    int t16  = lane & 15;                   // dim-chunk within group
    int wid  = threadIdx.x >> 6;
    int node = blockIdx.x * 4 + wid;        // NN%4==0, no tail
    int dg = deg_[node * DEGS];

    unsigned dof = (unsigned)t16 * 8u;      // first of this lane's 8 dims
    h8 qv = *(const h8*)&Aq[(unsigned)node * 256u + dof];
    h2 q0 = {qv[0], qv[1]}, q1 = {qv[2], qv[3]}, q2 = {qv[4], qv[5]}, q3 = {qv[6], qv[7]};

    float l = 0.f;
    h2 acc0 = {(_Float16)0.f, (_Float16)0.f};
    h2 acc1 = acc0, acc2 = acc0, acc3 = acc0;

    if (dg > 0) {
        int e0 = node * 64;                 // padded bucket row
        int e1 = e0 + dg;
        int iters = (dg + 3) >> 2;
        int last = e1 - 1;
        int ei = e0 + grp;                  // this group's edge for iter 0

        // prologue: pk + data for iter 0, pk for iter 1
        int pk_c = bucket[min(ei, last)];
        h8 nb_c = *(const h8*)&Ah[(unsigned)(pk_c & 0xFFFF) * 256u + dof];
        h8 rl_c = *(const h8*)&relh[(unsigned)(pk_c >> 16) * 128u + dof];
        int pk_n = bucket[min(ei + 4, last)];

#pragma unroll 2
        for (int it = 0; it < iters; ++it) {
            // prefetch iter it+2's pk and iter it+1's data
            int pk_n2 = bucket[min(ei + 8, last)];
            h8 nb_n = *(const h8*)&Ah[(unsigned)(pk_n & 0xFFFF) * 256u + dof];
            h8 rl_n = *(const h8*)&relh[(unsigned)(pk_n >> 16) * 128u + dof];

            h2 n0 = {nb_c[0], nb_c[1]}, n1 = {nb_c[2], nb_c[3]};
            h2 n2 = {nb_c[4], nb_c[5]}, n3 = {nb_c[6], nb_c[7]};
            h2 r0 = {rl_c[0], rl_c[1]}, r1 = {rl_c[2], rl_c[3]};
            h2 r2 = {rl_c[4], rl_c[5]}, r3 = {rl_c[6], rl_c[7]};

            h2 sd = n0 * tanh_h2(q0 + r0);
            sd = n1 * tanh_h2(q1 + r1) + sd;
            sd = n2 * tanh_h2(q2 + r2) + sd;
            sd = n3 * tanh_h2(q3 + r3) + sd;
            float s = (float)sd.x + (float)sd.y;

            // reduce all 4 groups at once: 4 row_shr adds -> lane15 of each row
            s = dpp_add<0x111, 0xF>(s);
            s = dpp_add<0x112, 0xF>(s);
            s = dpp_add<0x114, 0xF>(s);
            s = dpp_add<0x118, 0xF>(s);
            // broadcast each row's lane15 to the whole row: src=(lane&0x10)|0xF
            int si = __builtin_amdgcn_ds_swizzle(__builtin_bit_cast(int, s), 0x1F0);
            s = __builtin_bit_cast(float, si);

            float p = (ei < e1) ? __expf(s) : 0.f;
            l += p;
            _Float16 ph = (_Float16)p;
            h2 p2 = {ph, ph};
            acc0 = p2 * n0 + acc0;
            acc1 = p2 * n1 + acc1;
            acc2 = p2 * n2 + acc2;
            acc3 = p2 * n3 + acc3;

            ei += 4;
            pk_c = pk_n; pk_n = pk_n2;
            nb_c = nb_n; rl_c = rl_n;
        }

        // combine the 4 groups (same dims, disjoint edge subsets): xor 16, 32
#pragma unroll
        for (int off = 16; off <= 32; off <<= 1) {
            acc0 += __builtin_bit_cast(h2, __shfl_xor(__builtin_bit_cast(int, acc0), off, 64));
            acc1 += __builtin_bit_cast(h2, __shfl_xor(__builtin_bit_cast(int, acc1), off, 64));
            acc2 += __builtin_bit_cast(h2, __shfl_xor(__builtin_bit_cast(int, acc2), off, 64));
            acc3 += __builtin_bit_cast(h2, __shfl_xor(__builtin_bit_cast(int, acc3), off, 64));
            l += __shfl_xor(l, off, 64);
        }
    }

    float inv = (dg > 0) ? __builtin_amdgcn_rcpf(l) : 0.f;
    if (grp == 0) {
        _Float16 ih = (_Float16)inv;
        h2 iv = {ih, ih};
        h2 o0 = acc0 * iv, o1 = acc1 * iv, o2 = acc2 * iv, o3 = acc3 * iv;
        h8 o = {o0.x, o0.y, o1.x, o1.y, o2.x, o2.y, o3.x, o3.y};
        *(h8*)&Ah_out[(unsigned)node * 256u + 128u + dof] = o;
    }
}

// ---------- MFMA update: C[50000,128] = Ah[50000,256] @ W + b, fused epilogue ----
// LAST=false: write next layer's Ah only. LAST=true: write f32 out only.

template <bool LAST>
__global__ __launch_bounds__(256) void upd_k(const _Float16* __restrict__ Ah,
                                             const _Float16* __restrict__ wp,
                                             const float* __restrict__ bl,
                                             const int* __restrict__ deg_,
                                             const float* __restrict__ ent,
                                             float* __restrict__ out,
                                             _Float16* __restrict__ Ahn) {
    int lane = threadIdx.x & 63, wid = threadIdx.x >> 6;
    int quad = lane >> 4, n16 = lane & 15;
    int row0 = (blockIdx.x * 4 + wid) * 16;
    int arow = min(row0 + n16, NN - 1);          // clamped A row (pad rows discarded)

    f32x4 acc[8];
#pragma unroll
    for (int ct = 0; ct < 8; ++ct) acc[ct] = (f32x4){0.f, 0.f, 0.f, 0.f};

    const h8* aptr = (const h8*)(Ah + (size_t)arow * 256 + quad * 8);
#pragma unroll
    for (int ks = 0; ks < 8; ++ks) {
        h8 af = aptr[ks * 4];                    // stride 32 f16 per k-step
        const h8* bp = (const h8*)(wp + (((size_t)ks * 8) * 64 + lane) * 8);
#pragma unroll
        for (int ct = 0; ct < 8; ++ct) {
            h8 bfrag = bp[ct * 64];              // per-ct stride 64*8 f16
            acc[ct] = __builtin_amdgcn_mfma_f32_16x16x32_f16(af, bfrag, acc[ct], 0, 0, 0);
        }
    }

    float bias[8];
#pragma unroll
    for (int ct = 0; ct < 8; ++ct) bias[ct] = bl[ct * 16 + n16];

#pragma unroll
    for (int r = 0; r < 4; ++r) {
        int orow = row0 + quad * 4 + r;
        float h[8];
        float ss = 0.f;
#pragma unroll
        for (int ct = 0; ct < 8; ++ct) {
            float v = acc[ct][r] + bias[ct];
            v = (v > 0.f) ? v : 0.01f * v;
            h[ct] = v;
            ss += v * v;
        }
        ss = dpp_add<0x111, 0xF>(ss);
        ss = dpp_add<0x112, 0xF>(ss);
        ss = dpp_add<0x114, 0xF>(ss);
        ss = dpp_add<0x118, 0xF>(ss);
        ss = __shfl(ss, 15, 16);                 // broadcast lane15 of each 16-group
        float rinv = rsqrtf(ss);

        if (orow < NN) {
            bool iso = deg_[orow * DEGS] == 0;
#pragma unroll
            for (int ct = 0; ct < 8; ++ct) {
                int col = ct * 16 + n16;
                float v = h[ct] * rinv;
                if (iso) v = ent[(size_t)orow * DD + col];
                if (LAST) out[(size_t)orow * DD + col] = v;
                else      Ahn[(size_t)orow * 256 + col] = (_Float16)v;
            }
        }
    }
}

// ---------- launch ----------

extern "C" void kernel_launch(void* const* d_in, const int* in_sizes, int n_in,
                              void* d_out, int out_size, void* d_ws, size_t ws_size,
                              hipStream_t stream) {
    const float* ent = (const float*)d_in[0];   // [NN, DD]
    const float* rel = (const float*)d_in[1];   // [NR, DD]
    const float* W   = (const float*)d_in[2];   // [2, 2*DD, DD]
    const float* b   = (const float*)d_in[3];   // [2, DD]
    const int* edst  = (const int*)d_in[4];
    const int* enbr  = (const int*)d_in[5];
    const int* erel  = (const int*)d_in[6];
    float* out = (float*)d_out;                 // [NN, DD]

    char* ws = (char*)d_ws;
    size_t off = 0;
    auto alloc = [&](size_t bytes) -> void* {
        void* p = ws + off;
        off += (bytes + 255) & ~(size_t)255;
        return p;
    };
    int* deg       = (int*)alloc((size_t)NN * DEGS * 4);  // line-padded counters
    int* bucket    = (int*)alloc((size_t)NN * 64 * 4);    // 12.8 MB padded CSR
    _Float16* Ah0  = (_Float16*)alloc((size_t)NN * 256 * 2);
    _Float16* Ah1  = (_Float16*)alloc((size_t)NN * 256 * 2);
    _Float16* wp   = (_Float16*)alloc((size_t)2 * 8 * 8 * 64 * 8 * 2);
    _Float16* relh = (_Float16*)alloc((size_t)NR * DD * 2);

    // staging + bucket-CSR build in ONE kernel (fill blocks first in grid)
    hipMemsetAsync(deg, 0, (size_t)NN * DEGS * 4, stream);
    prep_k<<<FB + 6290, 256, 0, stream>>>(ent, rel, W, edst, enbr, erel,
                                          Ah0, relh, wp, deg, bucket);

    const _Float16* wp0 = wp;
    const _Float16* wp1 = wp + (size_t)8 * 8 * 64 * 8;
    int ublocks = (NN + 63) / 64;   // 782

    // layer 0: nb from Ah0, q from Ah0 (cols 0..127 = ent f16, kept pristine)
    agg_k<<<NN / 4, 256, 0, stream>>>(Ah0, Ah0, relh, deg, bucket, Ah0);
    upd_k<false><<<ublocks, 256, 0, stream>>>(Ah0, wp0, b, deg, ent, out, Ah1);

    // layer 1: nb from Ah1, q from Ah0
    agg_k<<<NN / 4, 256, 0, stream>>>(Ah1, Ah0, relh, deg, bucket, Ah1);
    upd_k<true><<<ublocks, 256, 0, stream>>>(Ah1, wp1, b + DD, deg, ent, out, Ah0);
}